// Round 11
// baseline (2182.764 us; speedup 1.0000x reference)
//
#include <hip/hip_runtime.h>
#include <hip/hip_bf16.h>
#include <stdint.h>

typedef __bf16 bf16x8 __attribute__((ext_vector_type(8)));
typedef float f32x4 __attribute__((ext_vector_type(4)));

// ---- helpers ------------------------------------------------------------

__device__ inline void gload_lds16(const void* g, void* lds) {
  __builtin_amdgcn_global_load_lds(
      (const __attribute__((address_space(1))) uint32_t*)(uintptr_t)g,
      (__attribute__((address_space(3))) uint32_t*)(uintptr_t)lds,
      16, 0, 0);
}

// Ordered ds_read_b128, base reg + literal offset (issue order preserved;
// DS completion in-order per wave -> counted lgkmcnt exact; suffix rule:
// outstanding set is always a suffix of issue order).
#define DSR(dst, base, OFF)                                         \
  asm volatile("ds_read_b128 %0, %1 offset:" #OFF                   \
               : "=v"(dst) : "v"(base))

#define LGKM(N) do {                                             \
    asm volatile("s_waitcnt lgkmcnt(" #N ")" ::: "memory");      \
    __builtin_amdgcn_sched_barrier(0);                           \
  } while (0)
#define VM(N) do {                                               \
    asm volatile("s_waitcnt vmcnt(" #N ")" ::: "memory");        \
    __builtin_amdgcn_sched_barrier(0);                           \
  } while (0)

__device__ inline short f2bf(float f) {
  union { float f; uint32_t u; } x; x.f = f;
  uint32_t u = x.u;
  u += 0x7fffu + ((u >> 16) & 1u);   // RNE
  return (short)(u >> 16);
}

#define BAR() do { asm volatile("" ::: "memory"); \
                   __builtin_amdgcn_s_barrier();  \
                   asm volatile("" ::: "memory"); } while (0)

// ---- fp32 -> bf16 convert (vectorized) ----------------------------------

__global__ __launch_bounds__(256) void cvt_f32_bf16(
    const float* __restrict__ in, short* __restrict__ out, int n4) {
  int i = blockIdx.x * 256 + threadIdx.x;
  if (i < n4) {
    float4 v = reinterpret_cast<const float4*>(in)[i];
    short4 o;
    o.x = f2bf(v.x); o.y = f2bf(v.y); o.z = f2bf(v.z); o.w = f2bf(v.w);
    reinterpret_cast<short4*>(out)[i] = o;
  }
}

// ---- GEMM: C[M,N] = A[M,K] @ B[N,K]^T, bf16 in, fp32 acc ---------------
// r8 base + CROSS-PHASE PRE-READ: the 12-read Q1 set (a0,b0) of tile t+1
// is issued in Ph4(t), whose MFMA (Q4) needs no new reads -> DS serves
// the burst UNDER Q4's MFMA + the publish barrier, instead of
// serializing in front of Q1. Per-phase reads: Ph1 b1(4), Ph2 a1(8),
// Ph3 none, Ph4 pre(12).
//
// 256x256 tile, BK=64, 8 waves (2Mx4N), per-wave 128x64 = acc[8][4] of
// mfma_f32_16x16x32_bf16 (swapped operands). LDS: 2 buf x 4 slots x
// [128x64] bf16 = 128 KiB; slots A0=+0, A1=+16384, B0=+32768,
// B1=+49152; buf1 = +65536 (separate base regs: 16-bit ds offset).
// Swizzle addr = slotrow*128 + ((kk*4+kq)^(fr&7))*16 (0-conflict,
// verified r2-r10).
//
// Phase template (2 barriers/phase, reads cross the mid-bar):
//   Ph1: rd b1q(4)  | stage A1(t+1)->nxt | BAR | LGKM(4)  Q1(aU,bU) | VM(8) BAR
//   Ph2: rd a1q(8)  | stage A0(t+2)->cur | BAR | LGKM(8)  Q2(aU,b1) | VM(8) BAR
//   Ph3:            | stage B0(t+2)->cur | BAR | LGKM(0)  Q3(a1,b1) | VM(8) BAR
//   Ph4: pre aP,bP(12) <- buf[nxt] | stage B1(t+2)->cur | LGKM(8) |
//        BAR | sched_barrier      Q4(a1,bU) | VM(8) BAR
// LGKM suffix proofs: Ph1 LGKM(4) leaves newest 4 = b1q -> pre-set done.
// Ph2 LGKM(8) leaves a1q -> b1q done. Ph3 LGKM(0) -> a1q done.
// VM(8) ledger (stage stream = r8: Ph1 A1(t+1), Ph2 A0(t+2), Ph3 B0(t+2),
// Ph4 B1(t+2); 2 gloads each): at each close, in-flight after VM(8) =
// the 4 newest half-tiles; the wait retires EXACTLY the half-tile read
// next phase: Ph3-close retires A0,B0(t+1) (pre-read Ph4); Ph4-close
// retires B1(t+1) (read Ph1'); Ph1'-close retires A1(t+1) (read Ph2').
// Prologue check: at Ph3(0)-close, 12 in flight, VM(8) retires
// A0(1),B0(1) staged in prologue. Clobber distances >= 1 full barrier
// after reader's LGKM completion (same as r8). Tail pair peeled:
// VM(0) at Ph1(nk-2)-close, no VMs after.
// Cross-tile reg sets X/Y alternate per tile parity (static names).
// Epilogue (verified r5-r10): lane&15=M-row, 4 acc regs = 4 consecutive
// N-cols. EPI=0: bias+relu^2->bf16 (short4); EPI=1: bias->f32 (float4).

template <int EPI>
__global__ __launch_bounds__(512, 2) void gemm_bt(
    const short* __restrict__ A, const short* __restrict__ B,
    const float* __restrict__ bias, void* __restrict__ Cout,
    int M, int N, int K) {
  __shared__ __align__(16) short lds[2][4][128 * 64];

  const int tid  = threadIdx.x;
  const int wave = tid >> 6;
  const int lane = tid & 63;
  const int wr = wave >> 2;          // 0..1 -> M half (128 rows)
  const int wc = wave & 3;           // 0..3 -> N quarter (64 cols)
  const int fr = lane & 15, kq = lane >> 4;

  // T1: bijective XCD swizzle (nwg % 8 == 0), column-major in-chunk
  const int nwg = gridDim.x;
  const int w = (blockIdx.x & 7) * (nwg >> 3) + (blockIdx.x >> 3);
  const int gy = M >> 8;
  const int brow = w % gy;
  const int bcol = w / gy;

  f32x4 acc[8][4];
#pragma unroll
  for (int m = 0; m < 8; ++m)
#pragma unroll
    for (int n = 0; n < 4; ++n)
      acc[m][n] = (f32x4){0.f, 0.f, 0.f, 0.f};

  const int nk = K >> 6;             // K-tiles of 64 (even, >=4)

  // ---- fragment read base regs: buf0 and buf1 separately (ds offset
  // immediates are 16-bit, 65536+22528 would overflow)
  const uint32_t LB = (uint32_t)(uintptr_t)&lds[0][0][0];
  uint32_t bA0[2], bB0[2], bA1[2], bB1[2];
  {
    const uint32_t x0 = (uint32_t)(((kq)     ^ (fr & 7)) * 16);
    const uint32_t x1 = (uint32_t)(((4 + kq) ^ (fr & 7)) * 16);
    const uint32_t ra = (uint32_t)((wr * 64 + fr) * 128);
    const uint32_t rb = (uint32_t)((wc * 32 + fr) * 128);
    bA0[0] = LB + ra + x0;            bA0[1] = LB + ra + x1;
    bB0[0] = LB + 32768u + rb + x0;   bB0[1] = LB + 32768u + rb + x1;
    bA1[0] = bA0[0] + 65536u;         bA1[1] = bA0[1] + 65536u;
    bB1[0] = bB0[0] + 65536u;         bB1[1] = bB0[1] + 65536u;
  }

  // ---- stage source addressing (inverse swizzle on global side)
  const int i0 = tid;
  const int gl0 = i0 ^ ((i0 >> 3) & 7);
  const int r0 = gl0 >> 3, c0 = gl0 & 7;
  const size_t rstep = (size_t)128 * K;

  const short* pA[2];
  const short* pB[2];
  {
    const int rb0 = (r0 >> 5) * 64 + (r0 & 31);
#pragma unroll
    for (int h = 0; h < 2; ++h) {
      pA[h] = A + (size_t)(brow * 256 + h * 64 + r0) * K + c0 * 8;
      pB[h] = B + (size_t)(bcol * 256 + rb0 + h * 32) * K + c0 * 8;
    }
  }

  const int dst0 = wave * 512, dst1 = 4096 + wave * 512;  // shorts in slot

#define STAGE(p, buf, slot)                              \
  do {                                                   \
    short* base_ = &lds[buf][slot][0];                   \
    gload_lds16((p), base_ + dst0);                      \
    gload_lds16((p) + rstep, base_ + dst1);              \
    (p) += 64;                                           \
  } while (0)

  // ---- fragment regs: X/Y = alternating cross-tile Q1 sets
  bf16x8 a0X[4][2], b0X[2][2], a0Y[4][2], b0Y[2][2];
  bf16x8 a1q[4][2], b1q[2][2];

  auto PRE = [&](bf16x8 (&aS)[4][2], bf16x8 (&bS)[2][2],
                 const uint32_t* bA_, const uint32_t* bB_) {
    DSR(aS[0][0], bA_[0], 0);     DSR(aS[0][1], bA_[1], 0);
    DSR(aS[1][0], bA_[0], 2048);  DSR(aS[1][1], bA_[1], 2048);
    DSR(aS[2][0], bA_[0], 4096);  DSR(aS[2][1], bA_[1], 4096);
    DSR(aS[3][0], bA_[0], 6144);  DSR(aS[3][1], bA_[1], 6144);
    DSR(bS[0][0], bB_[0], 0);     DSR(bS[0][1], bB_[1], 0);
    DSR(bS[1][0], bB_[0], 2048);  DSR(bS[1][1], bB_[1], 2048);
  };
  auto RDB1 = [&](const uint32_t* bB_) {
    DSR(b1q[0][0], bB_[0], 16384); DSR(b1q[0][1], bB_[1], 16384);
    DSR(b1q[1][0], bB_[0], 18432); DSR(b1q[1][1], bB_[1], 18432);
  };
  auto RDA1 = [&](const uint32_t* bA_) {
    DSR(a1q[0][0], bA_[0], 16384); DSR(a1q[0][1], bA_[1], 16384);
    DSR(a1q[1][0], bA_[0], 18432); DSR(a1q[1][1], bA_[1], 18432);
    DSR(a1q[2][0], bA_[0], 20480); DSR(a1q[2][1], bA_[1], 20480);
    DSR(a1q[3][0], bA_[0], 22528); DSR(a1q[3][1], bA_[1], 22528);
  };

  auto Q1 = [&](bf16x8 (&aS)[4][2], bf16x8 (&bS)[2][2]) {
#pragma unroll
    for (int m = 0; m < 4; ++m)
#pragma unroll
      for (int n = 0; n < 2; ++n)
#pragma unroll
        for (int kk = 0; kk < 2; ++kk)
          acc[m][n] = __builtin_amdgcn_mfma_f32_16x16x32_bf16(
              bS[n][kk], aS[m][kk], acc[m][n], 0, 0, 0);
  };
  auto Q2 = [&](bf16x8 (&aS)[4][2]) {
#pragma unroll
    for (int m = 0; m < 4; ++m)
#pragma unroll
      for (int n = 0; n < 2; ++n)
#pragma unroll
        for (int kk = 0; kk < 2; ++kk)
          acc[m][n + 2] = __builtin_amdgcn_mfma_f32_16x16x32_bf16(
              b1q[n][kk], aS[m][kk], acc[m][n + 2], 0, 0, 0);
  };
  auto Q3 = [&]() {
#pragma unroll
    for (int m = 0; m < 4; ++m)
#pragma unroll
      for (int n = 0; n < 2; ++n)
#pragma unroll
        for (int kk = 0; kk < 2; ++kk)
          acc[m + 4][n + 2] = __builtin_amdgcn_mfma_f32_16x16x32_bf16(
              b1q[n][kk], a1q[m][kk], acc[m + 4][n + 2], 0, 0, 0);
  };
  auto Q4 = [&](bf16x8 (&bS)[2][2]) {
#pragma unroll
    for (int m = 0; m < 4; ++m)
#pragma unroll
      for (int n = 0; n < 2; ++n)
#pragma unroll
        for (int kk = 0; kk < 2; ++kk)
          acc[m + 4][n] = __builtin_amdgcn_mfma_f32_16x16x32_bf16(
              bS[n][kk], a1q[m][kk], acc[m + 4][n], 0, 0, 0);
  };

#define PRIO_ON  __builtin_amdgcn_s_setprio(1)
#define PRIO_OFF __builtin_amdgcn_s_setprio(0)

  // ---- prologue: tile0 full + tile1 {A0,B0,B1}; publish; pre-read t0.
  STAGE(pA[0], 0, 0);   // A0(0)
  STAGE(pB[0], 0, 2);   // B0(0)
  STAGE(pB[1], 0, 3);   // B1(0)
  STAGE(pA[1], 0, 1);   // A1(0)
  STAGE(pA[0], 1, 0);   // A0(1)
  STAGE(pB[0], 1, 2);   // B0(1)
  STAGE(pB[1], 1, 3);   // B1(1)
  VM(6);                // tile 0 (oldest 8 gloads) landed
  BAR();
  PRE(a0X, b0X, bA0, bB0);     // Q1 set of tile 0

  const int niter = nk >> 1;
  for (int i = 0; i < niter - 1; ++i) {
    // ============ even tile (buf0; uses X, pre-reads Y) ============
    RDB1(bB0);  STAGE(pA[1], 1, 1);                 // Ph1
    BAR(); LGKM(4);
    PRIO_ON; Q1(a0X, b0X); PRIO_OFF;
    VM(8); BAR();
    RDA1(bA0);  STAGE(pA[0], 0, 0);                 // Ph2
    BAR(); LGKM(8);
    PRIO_ON; Q2(a0X); PRIO_OFF;
    VM(8); BAR();
    STAGE(pB[0], 0, 2);                             // Ph3
    BAR(); LGKM(0);
    PRIO_ON; Q3(); PRIO_OFF;
    VM(8); BAR();
    PRE(a0Y, b0Y, bA1, bB1);  STAGE(pB[1], 0, 3);   // Ph4
    LGKM(8);
    BAR(); __builtin_amdgcn_sched_barrier(0);
    PRIO_ON; Q4(b0X); PRIO_OFF;
    VM(8); BAR();

    // ============ odd tile (buf1; uses Y, pre-reads X) ============
    RDB1(bB1);  STAGE(pA[1], 0, 1);                 // Ph5
    BAR(); LGKM(4);
    PRIO_ON; Q1(a0Y, b0Y); PRIO_OFF;
    VM(8); BAR();
    RDA1(bA1);  STAGE(pA[0], 1, 0);                 // Ph6
    BAR(); LGKM(8);
    PRIO_ON; Q2(a0Y); PRIO_OFF;
    VM(8); BAR();
    STAGE(pB[0], 1, 2);                             // Ph7
    BAR(); LGKM(0);
    PRIO_ON; Q3(); PRIO_OFF;
    VM(8); BAR();
    PRE(a0X, b0X, bA0, bB0);  STAGE(pB[1], 1, 3);   // Ph8
    LGKM(8);
    BAR(); __builtin_amdgcn_sched_barrier(0);
    PRIO_ON; Q4(b0Y); PRIO_OFF;
    VM(8); BAR();
  }

  // ---- tail pair: t0 = nk-2 (even, buf0, stage only A1(nk-1)),
  //                 t1 = nk-1 (odd, buf1, no stages).
  RDB1(bB0);  STAGE(pA[1], 1, 1);                   // Ph1
  BAR(); LGKM(4);
  PRIO_ON; Q1(a0X, b0X); PRIO_OFF;
  VM(0); BAR();                                     // drain all
  RDA1(bA0);                                        // Ph2
  BAR(); LGKM(8);
  PRIO_ON; Q2(a0X); PRIO_OFF;
  BAR();
  BAR(); LGKM(0);                                   // Ph3
  PRIO_ON; Q3(); PRIO_OFF;
  BAR();
  PRE(a0Y, b0Y, bA1, bB1);                          // Ph4
  LGKM(8);
  BAR(); __builtin_amdgcn_sched_barrier(0);
  PRIO_ON; Q4(b0X); PRIO_OFF;
  BAR();
  RDB1(bB1);                                        // Ph5
  BAR(); LGKM(4);
  PRIO_ON; Q1(a0Y, b0Y); PRIO_OFF;
  BAR();
  RDA1(bA1);                                        // Ph6
  BAR(); LGKM(8);
  PRIO_ON; Q2(a0Y); PRIO_OFF;
  BAR();
  BAR(); LGKM(0);                                   // Ph7
  PRIO_ON; Q3(); PRIO_OFF;
  BAR();
  PRIO_ON; Q4(b0Y); PRIO_OFF;                       // Ph8

  // ---- epilogue (verified r5-r10): row = m*16+fr, cols = n*16+q*4+{0..3}
  const int q = lane >> 4;
  if (EPI == 0) {
    short* C = (short*)Cout;
#pragma unroll
    for (int m = 0; m < 8; ++m) {
      const int row = brow * 256 + wr * 128 + m * 16 + fr;
#pragma unroll
      for (int n = 0; n < 4; ++n) {
        const int col = bcol * 256 + wc * 64 + n * 16 + q * 4;
        const float4 bv = *(const float4*)&bias[col];
        short4 o;
        float v0 = acc[m][n][0] + bv.x; v0 = v0 > 0.f ? v0 * v0 : 0.f;
        float v1 = acc[m][n][1] + bv.y; v1 = v1 > 0.f ? v1 * v1 : 0.f;
        float v2 = acc[m][n][2] + bv.z; v2 = v2 > 0.f ? v2 * v2 : 0.f;
        float v3 = acc[m][n][3] + bv.w; v3 = v3 > 0.f ? v3 * v3 : 0.f;
        o.x = f2bf(v0); o.y = f2bf(v1); o.z = f2bf(v2); o.w = f2bf(v3);
        *(short4*)&C[(size_t)row * N + col] = o;
      }
    }
  } else {
    float* C = (float*)Cout;
#pragma unroll
    for (int m = 0; m < 8; ++m) {
      const int row = brow * 256 + wr * 128 + m * 16 + fr;
#pragma unroll
      for (int n = 0; n < 4; ++n) {
        const int col = bcol * 256 + wc * 64 + n * 16 + q * 4;
        const float4 bv = *(const float4*)&bias[col];
        float4 o;
        o.x = acc[m][n][0] + bv.x;
        o.y = acc[m][n][1] + bv.y;
        o.z = acc[m][n][2] + bv.z;
        o.w = acc[m][n][3] + bv.w;
        *(float4*)&C[(size_t)row * N + col] = o;
      }
    }
  }
#undef STAGE
}

// ---- launch -------------------------------------------------------------

extern "C" void kernel_launch(void* const* d_in, const int* in_sizes, int n_in,
                              void* d_out, int out_size, void* d_ws,
                              size_t ws_size, hipStream_t stream) {
  const float* x  = (const float*)d_in[0];
  const float* w1 = (const float*)d_in[1];
  const float* b1 = (const float*)d_in[2];
  const float* w2 = (const float*)d_in[3];
  const float* b2 = (const float*)d_in[4];
  float* out = (float*)d_out;

  const int H = in_sizes[2];            // 8192
  const int D = in_sizes[4];            // 2048
  const int M = in_sizes[0] / D;        // B*S = 8192

  short* xb  = (short*)d_ws;                 // M*D
  short* w1b = xb  + (size_t)M * D;          // H*D
  short* w2b = w1b + (size_t)H * D;          // D*H
  short* act = w2b + (size_t)D * H;          // M*H

  {
    int n4 = (M * D) / 4;
    cvt_f32_bf16<<<(n4 + 255) / 256, 256, 0, stream>>>(x, xb, n4);
    n4 = (H * D) / 4;
    cvt_f32_bf16<<<(n4 + 255) / 256, 256, 0, stream>>>(w1, w1b, n4);
    n4 = (D * H) / 4;
    cvt_f32_bf16<<<(n4 + 255) / 256, 256, 0, stream>>>(w2, w2b, n4);
  }

  // GEMM1: [M,D] @ [H,D]^T -> sqrelu -> act[M,H] (bf16)
  gemm_bt<0><<<(M / 256) * (H / 256), 512, 0, stream>>>(
      xb, w1b, b1, (void*)act, M, H, D);
  // GEMM2: [M,H] @ [D,H]^T -> + b2 -> out[M,D] (f32)
  gemm_bt<1><<<(M / 256) * (D / 256), 512, 0, stream>>>(
      act, w2b, b2, (void*)out, M, D, H);
}

// Round 12
// 624.079 us; speedup vs baseline: 3.4976x; 3.4976x over previous
//
#include <hip/hip_runtime.h>
#include <hip/hip_bf16.h>
#include <stdint.h>

typedef __bf16 bf16x8 __attribute__((ext_vector_type(8)));
typedef float f32x4 __attribute__((ext_vector_type(4)));

// ---- helpers ------------------------------------------------------------

__device__ inline void gload_lds16(const void* g, void* lds) {
  __builtin_amdgcn_global_load_lds(
      (const __attribute__((address_space(1))) uint32_t*)(uintptr_t)g,
      (__attribute__((address_space(3))) uint32_t*)(uintptr_t)lds,
      16, 0, 0);
}

// Ordered ds_read_b128, base reg + literal offset.
#define DSR(dst, base, OFF)                                         \
  asm volatile("ds_read_b128 %0, %1 offset:" #OFF                   \
               : "=v"(dst) : "v"(base))

#define LGKM(N) do {                                             \
    asm volatile("s_waitcnt lgkmcnt(" #N ")" ::: "memory");      \
    __builtin_amdgcn_sched_barrier(0);                           \
  } while (0)
#define VM(N) do {                                               \
    asm volatile("s_waitcnt vmcnt(" #N ")" ::: "memory");        \
    __builtin_amdgcn_sched_barrier(0);                           \
  } while (0)

__device__ inline short f2bf(float f) {
  union { float f; uint32_t u; } x; x.f = f;
  uint32_t u = x.u;
  u += 0x7fffu + ((u >> 16) & 1u);   // RNE
  return (short)(u >> 16);
}

#define BAR() do { asm volatile("" ::: "memory"); \
                   __builtin_amdgcn_s_barrier();  \
                   asm volatile("" ::: "memory"); } while (0)

// ---- fp32 -> bf16 convert (vectorized) ----------------------------------

__global__ __launch_bounds__(256) void cvt_f32_bf16(
    const float* __restrict__ in, short* __restrict__ out, int n4) {
  int i = blockIdx.x * 256 + threadIdx.x;
  if (i < n4) {
    float4 v = reinterpret_cast<const float4*>(in)[i];
    short4 o;
    o.x = f2bf(v.x); o.y = f2bf(v.y); o.z = f2bf(v.z); o.w = f2bf(v.w);
    reinterpret_cast<short4*>(out)[i] = o;
  }
}

// ---- GEMM: C[M,N] = A[M,K] @ B[N,K]^T, bf16 in, fp32 acc ---------------
// 4-WAVE / per-wave 128x128 variant of r8. Rationale: LDS read traffic
// scales with per-wave tile perimeter; 4 waves x 128x128 cuts per-CU DS
// load per K-tile from 2304 to ~1536 cyc while MFMA stays 2484 -> the
// kernel becomes MFMA-dominant. 256 threads = 1 wave/SIMD -> unified
// VGPR budget 512 (acc 256 + frags 128 fits; impossible at 512 thr).
//
// 256x256 tile, BK=64, 4 waves (2Mx2N), per-wave 128x128 = acc[8][8] of
// mfma_f32_16x16x32_bf16 (swapped operands, verified r5-r11).
// LDS: 2 buf x 4 slots x [128x64] bf16 = 128 KiB; slots (symmetric A/B):
//   A0=+0 (m-frags 0-3), A1=+16384 (m 4-7), B0=+32768 (n 0-3),
//   B1=+49152 (n 4-7); buf1 = +65536. Slot row r (0..127): tile row =
//   (r>>6)*128 + s*64 + (r&63); read row = w*64 + f*16 + fr (w=wr|wc).
// Swizzle addr = slotrow*128 + ((kk*4+kq)^(fr&7))*16 (0-conflict,
// verified r2-r11).
//
// Stage: 256 thr -> 4 gloads/slot; chunk k covers slot rows 32k+[0,32),
// src row offsets {0,32,128,160} from (s*64 + r0); dst = k*2048 +
// wave*512 shorts.
// Phases per tile t (cur=t&1): reads cross mid-BAR, LGKM(0) after:
//   Ph1: rd a0q(8)+bq0(8) | stage A1(t+1)->nxt | LGKM(8) BAR LGKM(0)
//        prio Q1(m0-3,n0-3) 32xMFMA | VM(20) BAR
//   Ph2: rd bq1(8) | stage A0(t+2)->cur | BAR LGKM(0) Q2(m0-3,n4-7) | VM(20) BAR
//   Ph3: rd a1q(8) | stage B0(t+2)->cur | BAR LGKM(0) Q3(m4-7,n4-7) | VM(20) BAR
//   Ph4:           | stage B1(t+2)->cur | BAR Q4(m4-7,n0-3) | VM(20) BAR
// VM(20) ledger (stages 4 gloads each; steady outstanding 24->20/phase):
// entering tile t outstanding 20 = {B1(t),A1(t),A0(t+1),B0(t+1),B1(t+1)};
// Ph1 +A1(t+1)=24 -> VM(20) retires B1(t) (read Ph2 ✓); Ph2 retires A1(t)
// (read Ph3 ✓); Ph3 retires A0(t+1), Ph4 retires B0(t+1) (both read
// Ph1(t+1) ✓). Prologue traced: 12 outstanding after VM(12); Ph3(0)/
// Ph4(0) retire A0(1)/B0(1) ✓. Clobber: every restage >=1 closing BAR
// after that slot's reads completed (LGKM(0) precedes same phase close).
// Tail pair (no more stages): Ph1(nk-2) VM(20); then descending
// VM(16),VM(12),VM(8) | VM(4),VM(0) retire exactly the next read's
// half-tile. Epilogue: lane&15=M-row; 4 acc regs = 4 consecutive N-cols.
// EPI=0: bias+relu^2->bf16 (short4); EPI=1: bias->f32 (float4).

template <int EPI>
__global__ __launch_bounds__(256, 1) void gemm_bt(
    const short* __restrict__ A, const short* __restrict__ B,
    const float* __restrict__ bias, void* __restrict__ Cout,
    int M, int N, int K) {
  __shared__ __align__(16) short lds[2][4][128 * 64];

  const int tid  = threadIdx.x;
  const int wave = tid >> 6;
  const int lane = tid & 63;
  const int wr = wave >> 1;          // 0..1 -> M half (128 rows)
  const int wc = wave & 1;           // 0..1 -> N half (128 cols)
  const int fr = lane & 15, kq = lane >> 4;

  // T1: bijective XCD swizzle (nwg % 8 == 0), column-major in-chunk
  const int nwg = gridDim.x;
  const int w = (blockIdx.x & 7) * (nwg >> 3) + (blockIdx.x >> 3);
  const int gy = M >> 8;
  const int brow = w % gy;
  const int bcol = w / gy;

  f32x4 acc[8][8];
#pragma unroll
  for (int m = 0; m < 8; ++m)
#pragma unroll
    for (int n = 0; n < 8; ++n)
      acc[m][n] = (f32x4){0.f, 0.f, 0.f, 0.f};

  const int nk = K >> 6;             // K-tiles of 64 (even, >=4)

  // ---- fragment read base regs (buf0 and buf1; ds offsets <= 22528)
  const uint32_t LB = (uint32_t)(uintptr_t)&lds[0][0][0];
  uint32_t bA0[2], bB0[2], bA1b[2], bB1b[2];
  {
    const uint32_t x0 = (uint32_t)(((kq)     ^ (fr & 7)) * 16);
    const uint32_t x1 = (uint32_t)(((4 + kq) ^ (fr & 7)) * 16);
    const uint32_t ra = (uint32_t)((wr * 64 + fr) * 128);
    const uint32_t rb = (uint32_t)((wc * 64 + fr) * 128);
    bA0[0] = LB + ra + x0;            bA0[1] = LB + ra + x1;
    bB0[0] = LB + 32768u + rb + x0;   bB0[1] = LB + 32768u + rb + x1;
    bA1b[0] = bA0[0] + 65536u;        bA1b[1] = bA0[1] + 65536u;
    bB1b[0] = bB0[0] + 65536u;        bB1b[1] = bB0[1] + 65536u;
  }

  // ---- stage source addressing (inverse swizzle on global side)
  const int gl0 = (tid ^ ((tid >> 3) & 7)) & 255;
  const int r0 = gl0 >> 3, c0 = gl0 & 7;        // r0 in 0..31

  const short* pA[2];
  const short* pB[2];
#pragma unroll
  for (int s = 0; s < 2; ++s) {
    pA[s] = A + (size_t)(brow * 256 + s * 64 + r0) * K + c0 * 8;
    pB[s] = B + (size_t)(bcol * 256 + s * 64 + r0) * K + c0 * 8;
  }
  const size_t rk32 = (size_t)32 * K, rk128 = (size_t)128 * K;
  const size_t rk160 = (size_t)160 * K;
  const int dstw = wave * 512;       // shorts

#define STAGE(p, buf, slot)                                       \
  do {                                                            \
    short* base_ = &lds[buf][slot][0];                            \
    gload_lds16((p),          base_ + dstw);                      \
    gload_lds16((p) + rk32,   base_ + 2048 + dstw);               \
    gload_lds16((p) + rk128,  base_ + 4096 + dstw);               \
    gload_lds16((p) + rk160,  base_ + 6144 + dstw);               \
    (p) += 64;                                                    \
  } while (0)

  // ---- fragment regs + clusters (swapped operands, static indices)
  bf16x8 a0q[4][2], a1q[4][2], bq0[4][2], bq1[4][2];
  auto Q1 = [&]() {
#pragma unroll
    for (int m = 0; m < 4; ++m)
#pragma unroll
      for (int n = 0; n < 4; ++n)
#pragma unroll
        for (int kk = 0; kk < 2; ++kk)
          acc[m][n] = __builtin_amdgcn_mfma_f32_16x16x32_bf16(
              bq0[n][kk], a0q[m][kk], acc[m][n], 0, 0, 0);
  };
  auto Q2 = [&]() {
#pragma unroll
    for (int m = 0; m < 4; ++m)
#pragma unroll
      for (int n = 0; n < 4; ++n)
#pragma unroll
        for (int kk = 0; kk < 2; ++kk)
          acc[m][n + 4] = __builtin_amdgcn_mfma_f32_16x16x32_bf16(
              bq1[n][kk], a0q[m][kk], acc[m][n + 4], 0, 0, 0);
  };
  auto Q3 = [&]() {
#pragma unroll
    for (int m = 0; m < 4; ++m)
#pragma unroll
      for (int n = 0; n < 4; ++n)
#pragma unroll
        for (int kk = 0; kk < 2; ++kk)
          acc[m + 4][n + 4] = __builtin_amdgcn_mfma_f32_16x16x32_bf16(
              bq1[n][kk], a1q[m][kk], acc[m + 4][n + 4], 0, 0, 0);
  };
  auto Q4 = [&]() {
#pragma unroll
    for (int m = 0; m < 4; ++m)
#pragma unroll
      for (int n = 0; n < 4; ++n)
#pragma unroll
        for (int kk = 0; kk < 2; ++kk)
          acc[m + 4][n] = __builtin_amdgcn_mfma_f32_16x16x32_bf16(
              bq0[n][kk], a1q[m][kk], acc[m + 4][n], 0, 0, 0);
  };
  auto RD_A0 = [&](const uint32_t* bA_) {
    DSR(a0q[0][0], bA_[0], 0);     DSR(a0q[0][1], bA_[1], 0);
    DSR(a0q[1][0], bA_[0], 2048);  DSR(a0q[1][1], bA_[1], 2048);
    DSR(a0q[2][0], bA_[0], 4096);  DSR(a0q[2][1], bA_[1], 4096);
    DSR(a0q[3][0], bA_[0], 6144);  DSR(a0q[3][1], bA_[1], 6144);
  };
  auto RD_B0 = [&](const uint32_t* bB_) {
    DSR(bq0[0][0], bB_[0], 0);     DSR(bq0[0][1], bB_[1], 0);
    DSR(bq0[1][0], bB_[0], 2048);  DSR(bq0[1][1], bB_[1], 2048);
    DSR(bq0[2][0], bB_[0], 4096);  DSR(bq0[2][1], bB_[1], 4096);
    DSR(bq0[3][0], bB_[0], 6144);  DSR(bq0[3][1], bB_[1], 6144);
  };
  auto RD_B1 = [&](const uint32_t* bB_) {
    DSR(bq1[0][0], bB_[0], 16384); DSR(bq1[0][1], bB_[1], 16384);
    DSR(bq1[1][0], bB_[0], 18432); DSR(bq1[1][1], bB_[1], 18432);
    DSR(bq1[2][0], bB_[0], 20480); DSR(bq1[2][1], bB_[1], 20480);
    DSR(bq1[3][0], bB_[0], 22528); DSR(bq1[3][1], bB_[1], 22528);
  };
  auto RD_A1 = [&](const uint32_t* bA_) {
    DSR(a1q[0][0], bA_[0], 16384); DSR(a1q[0][1], bA_[1], 16384);
    DSR(a1q[1][0], bA_[0], 18432); DSR(a1q[1][1], bA_[1], 18432);
    DSR(a1q[2][0], bA_[0], 20480); DSR(a1q[2][1], bA_[1], 20480);
    DSR(a1q[3][0], bA_[0], 22528); DSR(a1q[3][1], bA_[1], 22528);
  };

#define PRIO_ON  __builtin_amdgcn_s_setprio(1)
#define PRIO_OFF __builtin_amdgcn_s_setprio(0)

  // ---- prologue: tile0 full + tile1 {A0,B0,B1}; publish tile 0.
  STAGE(pA[0], 0, 0);   // A0(0)
  STAGE(pB[0], 0, 2);   // B0(0)
  STAGE(pB[1], 0, 3);   // B1(0)
  STAGE(pA[1], 0, 1);   // A1(0)
  STAGE(pA[0], 1, 0);   // A0(1)
  STAGE(pB[0], 1, 2);   // B0(1)
  STAGE(pB[1], 1, 3);   // B1(1)
  VM(12);               // tile 0 (oldest 16 gloads) landed
  BAR();

  const int niter = nk >> 1;
  for (int i = 0; i < niter - 1; ++i) {
    // ============ even tile (buf0) ============
    RD_A0(bA0); RD_B0(bB0);  STAGE(pA[1], 1, 1);      // Ph1
    LGKM(8);
    BAR(); LGKM(0);
    PRIO_ON; Q1(); PRIO_OFF;
    VM(20); BAR();
    RD_B1(bB0);  STAGE(pA[0], 0, 0);                  // Ph2
    BAR(); LGKM(0);
    PRIO_ON; Q2(); PRIO_OFF;
    VM(20); BAR();
    RD_A1(bA0);  STAGE(pB[0], 0, 2);                  // Ph3
    BAR(); LGKM(0);
    PRIO_ON; Q3(); PRIO_OFF;
    VM(20); BAR();
    STAGE(pB[1], 0, 3);                               // Ph4
    BAR();
    PRIO_ON; Q4(); PRIO_OFF;
    VM(20); BAR();

    // ============ odd tile (buf1) ============
    RD_A0(bA1b); RD_B0(bB1b);  STAGE(pA[1], 0, 1);    // Ph5
    LGKM(8);
    BAR(); LGKM(0);
    PRIO_ON; Q1(); PRIO_OFF;
    VM(20); BAR();
    RD_B1(bB1b);  STAGE(pA[0], 1, 0);                 // Ph6
    BAR(); LGKM(0);
    PRIO_ON; Q2(); PRIO_OFF;
    VM(20); BAR();
    RD_A1(bA1b);  STAGE(pB[0], 1, 2);                 // Ph7
    BAR(); LGKM(0);
    PRIO_ON; Q3(); PRIO_OFF;
    VM(20); BAR();
    STAGE(pB[1], 1, 3);                               // Ph8
    BAR();
    PRIO_ON; Q4(); PRIO_OFF;
    VM(20); BAR();
  }

  // ---- tail pair: tile nk-2 (buf0; only stage = A1(nk-1)), tile nk-1.
  RD_A0(bA0); RD_B0(bB0);  STAGE(pA[1], 1, 1);        // Ph1
  LGKM(8);
  BAR(); LGKM(0);
  PRIO_ON; Q1(); PRIO_OFF;
  VM(20); BAR();                                      // retires B1(nk-2)
  RD_B1(bB0);                                         // Ph2
  BAR(); LGKM(0);
  PRIO_ON; Q2(); PRIO_OFF;
  VM(16); BAR();                                      // retires A1(nk-2)
  RD_A1(bA0);                                         // Ph3
  BAR(); LGKM(0);
  PRIO_ON; Q3(); PRIO_OFF;
  VM(12); BAR();                                      // retires A0(nk-1)
  BAR();                                              // Ph4
  PRIO_ON; Q4(); PRIO_OFF;
  VM(8); BAR();                                       // retires B0(nk-1)
  RD_A0(bA1b); RD_B0(bB1b);                           // Ph5
  LGKM(8);
  BAR(); LGKM(0);
  PRIO_ON; Q1(); PRIO_OFF;
  VM(4); BAR();                                       // retires B1(nk-1)
  RD_B1(bB1b);                                        // Ph6
  BAR(); LGKM(0);
  PRIO_ON; Q2(); PRIO_OFF;
  VM(0); BAR();                                       // retires A1(nk-1)
  RD_A1(bA1b);                                        // Ph7
  BAR(); LGKM(0);
  PRIO_ON; Q3(); PRIO_OFF;
  BAR();
  PRIO_ON; Q4(); PRIO_OFF;                            // Ph8

  // ---- epilogue (verified r5-r11): row = m*16+fr, cols = n*16+q*4+{0..3}
  const int q = lane >> 4;
  if (EPI == 0) {
    short* C = (short*)Cout;
#pragma unroll
    for (int m = 0; m < 8; ++m) {
      const int row = brow * 256 + wr * 128 + m * 16 + fr;
#pragma unroll
      for (int n = 0; n < 8; ++n) {
        const int col = bcol * 256 + wc * 128 + n * 16 + q * 4;
        const float4 bv = *(const float4*)&bias[col];
        short4 o;
        float v0 = acc[m][n][0] + bv.x; v0 = v0 > 0.f ? v0 * v0 : 0.f;
        float v1 = acc[m][n][1] + bv.y; v1 = v1 > 0.f ? v1 * v1 : 0.f;
        float v2 = acc[m][n][2] + bv.z; v2 = v2 > 0.f ? v2 * v2 : 0.f;
        float v3 = acc[m][n][3] + bv.w; v3 = v3 > 0.f ? v3 * v3 : 0.f;
        o.x = f2bf(v0); o.y = f2bf(v1); o.z = f2bf(v2); o.w = f2bf(v3);
        *(short4*)&C[(size_t)row * N + col] = o;
      }
    }
  } else {
    float* C = (float*)Cout;
#pragma unroll
    for (int m = 0; m < 8; ++m) {
      const int row = brow * 256 + wr * 128 + m * 16 + fr;
#pragma unroll
      for (int n = 0; n < 8; ++n) {
        const int col = bcol * 256 + wc * 128 + n * 16 + q * 4;
        const float4 bv = *(const float4*)&bias[col];
        float4 o;
        o.x = acc[m][n][0] + bv.x;
        o.y = acc[m][n][1] + bv.y;
        o.z = acc[m][n][2] + bv.z;
        o.w = acc[m][n][3] + bv.w;
        *(float4*)&C[(size_t)row * N + col] = o;
      }
    }
  }
#undef STAGE
}

// ---- launch -------------------------------------------------------------

extern "C" void kernel_launch(void* const* d_in, const int* in_sizes, int n_in,
                              void* d_out, int out_size, void* d_ws,
                              size_t ws_size, hipStream_t stream) {
  const float* x  = (const float*)d_in[0];
  const float* w1 = (const float*)d_in[1];
  const float* b1 = (const float*)d_in[2];
  const float* w2 = (const float*)d_in[3];
  const float* b2 = (const float*)d_in[4];
  float* out = (float*)d_out;

  const int H = in_sizes[2];            // 8192
  const int D = in_sizes[4];            // 2048
  const int M = in_sizes[0] / D;        // B*S = 8192

  short* xb  = (short*)d_ws;                 // M*D
  short* w1b = xb  + (size_t)M * D;          // H*D
  short* w2b = w1b + (size_t)H * D;          // D*H
  short* act = w2b + (size_t)D * H;          // M*H

  {
    int n4 = (M * D) / 4;
    cvt_f32_bf16<<<(n4 + 255) / 256, 256, 0, stream>>>(x, xb, n4);
    n4 = (H * D) / 4;
    cvt_f32_bf16<<<(n4 + 255) / 256, 256, 0, stream>>>(w1, w1b, n4);
    n4 = (D * H) / 4;
    cvt_f32_bf16<<<(n4 + 255) / 256, 256, 0, stream>>>(w2, w2b, n4);
  }

  // GEMM1: [M,D] @ [H,D]^T -> sqrelu -> act[M,H] (bf16)
  gemm_bt<0><<<(M / 256) * (H / 256), 256, 0, stream>>>(
      xb, w1b, b1, (void*)act, M, H, D);
  // GEMM2: [M,H] @ [D,H]^T -> + b2 -> out[M,D] (f32)
  gemm_bt<1><<<(M / 256) * (D / 256), 256, 0, stream>>>(
      act, w2b, b2, (void*)out, M, D, H);
}

// Round 13
// 546.313 us; speedup vs baseline: 3.9954x; 1.1423x over previous
//
#include <hip/hip_runtime.h>
#include <hip/hip_bf16.h>
#include <stdint.h>

typedef __bf16 bf16x8 __attribute__((ext_vector_type(8)));
typedef float f32x4 __attribute__((ext_vector_type(4)));

// ---- helpers ------------------------------------------------------------

__device__ inline void gload_lds16(const void* g, void* lds) {
  __builtin_amdgcn_global_load_lds(
      (const __attribute__((address_space(1))) uint32_t*)(uintptr_t)g,
      (__attribute__((address_space(3))) uint32_t*)(uintptr_t)lds,
      16, 0, 0);
}

// Ordered LDS vector read (volatile asm: issue order preserved; DS
// completion in-order per wave -> counted lgkmcnt is exact).
__device__ inline bf16x8 ds_readv(uint32_t addr) {
  bf16x8 r;
  asm volatile("ds_read_b128 %0, %1" : "=v"(r) : "v"(addr));
  return r;
}

#define LGKM(N) do {                                             \
    asm volatile("s_waitcnt lgkmcnt(" #N ")" ::: "memory");      \
    __builtin_amdgcn_sched_barrier(0);                           \
  } while (0)
#define VM(N) do {                                               \
    asm volatile("s_waitcnt vmcnt(" #N ")" ::: "memory");        \
    __builtin_amdgcn_sched_barrier(0);                           \
  } while (0)

__device__ inline short f2bf(float f) {
  union { float f; uint32_t u; } x; x.f = f;
  uint32_t u = x.u;
  u += 0x7fffu + ((u >> 16) & 1u);   // RNE
  return (short)(u >> 16);
}

#define BAR() do { asm volatile("" ::: "memory"); \
                   __builtin_amdgcn_s_barrier();  \
                   asm volatile("" ::: "memory"); } while (0)

// ---- fp32 -> bf16 convert (vectorized) ----------------------------------

__global__ __launch_bounds__(256) void cvt_f32_bf16(
    const float* __restrict__ in, short* __restrict__ out, int n4) {
  int i = blockIdx.x * 256 + threadIdx.x;
  if (i < n4) {
    float4 v = reinterpret_cast<const float4*>(in)[i];
    short4 o;
    o.x = f2bf(v.x); o.y = f2bf(v.y); o.z = f2bf(v.z); o.w = f2bf(v.w);
    reinterpret_cast<short4*>(out)[i] = o;
  }
}

// ---- GEMM: C[M,N] = A[M,K] @ B[N,K]^T, bf16 in, fp32 acc ---------------
// r8 (best: 266us/GEMM, MfmaUtil 45%) with HALVED sync ops: stages moved
// POST-barrier -> the 4 closing barriers per tile are deleted. One
// barrier per phase: {reads | [LGKM(8)] [VM(8)] | BAR | LGKM(0) |
// stage | setprio MFMA setprio}.
//
// 256x256 tile, BK=64, 8 waves (2Mx4N), per-wave 128x64 = acc[8][4] of
// mfma_f32_16x16x32_bf16 (swapped operands). LDS: 2 buf x 4 slots x
// [128x64] bf16 = 128 KiB; A0=+0, A1=+16384, B0=+32768, B1=+49152;
// buf1=+65536. Swizzle P = g ^ (r&7) (0 conflicts, verified r2-r12).
//
// Per tile t (cur=t&1, nxt=cur^1), stage stream unchanged from r8:
//   Ph1: rd a0q(8)+bq0(4) | LGKM(8) VM(8) BAR LGKM(0) | stage A1(t+1)
//        ->nxt | Q1(m0-3,n0-1)
//   Ph2: rd bq1(4)        | VM(8) BAR LGKM(0) | stage A0(t+2)->cur | Q2
//   Ph3: rd a1q(8)        | BAR LGKM(0)       | stage B0(t+2)->cur | Q3
//   Ph4: (no reads)       | VM(8) BAR         | stage B1(t+2)->cur | Q4
// Readiness ledger (stages 2 gloads, issued post-BAR of their phase):
//   VM(8) pre-BAR_1(t): outstanding {B1(t),A1(t),A0(t+1),B0(t+1),
//     B1(t+1)}=10 -> retires B1(t), read Ph2(t) ✓.
//   VM(8) pre-BAR_2(t): {A1(t),A0..B1(t+1),A1(t+1)}=10 -> retires
//     A1(t), read Ph3(t) ✓.
//   VM(8) pre-BAR_4(t): {A0(t+1)..A1(t+1),A0(t+2),B0(t+2)}=12 ->
//     retires A0(t+1),B0(t+1), read Ph1(t+1) ✓.  (No VM at Ph3.)
//   Prologue (14 gloads, VM(6) leaves A0,B0,B1(1)) traced for t=0,1:
//   all VM(8) sites retire exactly the slots read next ✓.
// Clobber ledger: stage into S post-BAR_k; S's readers' ds_reads
//   completed before they reached the PREVIOUS barrier (LGKM(0) precedes
//   each wave's next BAR): A1 dist 2 phases, A0 dist 1 (post-BAR_2 >
//   BAR_1 where reads of A0 were complete), B0/B1 dist 2 ✓.
// Tail pair (t=nk-2,nk-1): VM(0) at the VM sites (full drain, 2 tiles).
// Epilogue (verified r5-r12): lane&15=M-row, 4 acc regs = 4 consecutive
// N-cols. EPI=0: bias+relu^2->bf16 (short4); EPI=1: bias->f32 (float4).

template <int EPI>
__global__ __launch_bounds__(512, 2) void gemm_bt(
    const short* __restrict__ A, const short* __restrict__ B,
    const float* __restrict__ bias, void* __restrict__ Cout,
    int M, int N, int K) {
  __shared__ __align__(16) short lds[2][4][128 * 64];

  const int tid  = threadIdx.x;
  const int wave = tid >> 6;
  const int lane = tid & 63;
  const int wr = wave >> 2;          // 0..1 -> M half (128 rows)
  const int wc = wave & 3;           // 0..3 -> N quarter (64 cols)
  const int fr = lane & 15, kq = lane >> 4;

  // T1: bijective XCD swizzle (nwg % 8 == 0), column-major in-chunk
  const int nwg = gridDim.x;
  const int w = (blockIdx.x & 7) * (nwg >> 3) + (blockIdx.x >> 3);
  const int gy = M >> 8;
  const int brow = w % gy;
  const int bcol = w / gy;

  f32x4 acc[8][4];
#pragma unroll
  for (int m = 0; m < 8; ++m)
#pragma unroll
    for (int n = 0; n < 4; ++n)
      acc[m][n] = (f32x4){0.f, 0.f, 0.f, 0.f};

  const int nk = K >> 6;             // K-tiles of 64 (even; nk>=4 here)

  // ---- T2 swizzle: addr = slotrow*128 + ((kk*4+kq)^(fr&7))*16
  const uint32_t LB = (uint32_t)(uintptr_t)&lds[0][0][0];
  uint32_t aA[4][2], aB[2][2];
#pragma unroll
  for (int m = 0; m < 4; ++m)
#pragma unroll
    for (int kk = 0; kk < 2; ++kk) {
      int r = wr * 64 + m * 16 + fr;
      int g = r * 8 + kk * 4 + kq;
      aA[m][kk] = LB + (uint32_t)((g ^ (r & 7)) * 16);
    }
#pragma unroll
  for (int n = 0; n < 2; ++n)
#pragma unroll
    for (int kk = 0; kk < 2; ++kk) {
      int r = wc * 32 + n * 16 + fr;
      int g = r * 8 + kk * 4 + kq;
      aB[n][kk] = LB + (uint32_t)((g ^ (r & 7)) * 16);
    }

  // ---- stage source addressing (inverse swizzle on global side)
  const int i0 = tid;
  const int gl0 = i0 ^ ((i0 >> 3) & 7);
  const int r0 = gl0 >> 3, c0 = gl0 & 7;
  const size_t rstep = (size_t)128 * K;

  const short* pA[2];
  const short* pB[2];
  {
    const int rb0 = (r0 >> 5) * 64 + (r0 & 31);
#pragma unroll
    for (int h = 0; h < 2; ++h) {
      pA[h] = A + (size_t)(brow * 256 + h * 64 + r0) * K + c0 * 8;
      pB[h] = B + (size_t)(bcol * 256 + rb0 + h * 32) * K + c0 * 8;
    }
  }

  const int dst0 = wave * 512, dst1 = 4096 + wave * 512;  // shorts in slot

#define STAGE(p, buf, slot)                              \
  do {                                                   \
    short* base_ = &lds[buf][slot][0];                   \
    gload_lds16((p), base_ + dst0);                      \
    gload_lds16((p) + rstep, base_ + dst1);              \
    (p) += 64;                                           \
  } while (0)

  // fragment regs + quadrant clusters (swapped operands)
  bf16x8 a0q[4][2], a1q[4][2], bq0[2][2], bq1[2][2];
  auto Q1 = [&]() {
#pragma unroll
    for (int m = 0; m < 4; ++m)
#pragma unroll
      for (int n = 0; n < 2; ++n)
#pragma unroll
        for (int kk = 0; kk < 2; ++kk)
          acc[m][n] = __builtin_amdgcn_mfma_f32_16x16x32_bf16(
              bq0[n][kk], a0q[m][kk], acc[m][n], 0, 0, 0);
  };
  auto Q2 = [&]() {
#pragma unroll
    for (int m = 0; m < 4; ++m)
#pragma unroll
      for (int n = 0; n < 2; ++n)
#pragma unroll
        for (int kk = 0; kk < 2; ++kk)
          acc[m][n + 2] = __builtin_amdgcn_mfma_f32_16x16x32_bf16(
              bq1[n][kk], a0q[m][kk], acc[m][n + 2], 0, 0, 0);
  };
  auto Q3 = [&]() {
#pragma unroll
    for (int m = 0; m < 4; ++m)
#pragma unroll
      for (int n = 0; n < 2; ++n)
#pragma unroll
        for (int kk = 0; kk < 2; ++kk)
          acc[m + 4][n + 2] = __builtin_amdgcn_mfma_f32_16x16x32_bf16(
              bq1[n][kk], a1q[m][kk], acc[m + 4][n + 2], 0, 0, 0);
  };
  auto Q4 = [&]() {
#pragma unroll
    for (int m = 0; m < 4; ++m)
#pragma unroll
      for (int n = 0; n < 2; ++n)
#pragma unroll
        for (int kk = 0; kk < 2; ++kk)
          acc[m + 4][n] = __builtin_amdgcn_mfma_f32_16x16x32_bf16(
              bq0[n][kk], a1q[m][kk], acc[m + 4][n], 0, 0, 0);
  };
  auto RD_A0 = [&](uint32_t cb) {
#pragma unroll
    for (int m = 0; m < 4; ++m)
#pragma unroll
      for (int kk = 0; kk < 2; ++kk)
        a0q[m][kk] = ds_readv(aA[m][kk] + cb);
  };
  auto RD_A1 = [&](uint32_t cb) {
#pragma unroll
    for (int m = 0; m < 4; ++m)
#pragma unroll
      for (int kk = 0; kk < 2; ++kk)
        a1q[m][kk] = ds_readv(aA[m][kk] + cb + 16384u);
  };
  auto RD_B0 = [&](uint32_t cb) {
#pragma unroll
    for (int n = 0; n < 2; ++n)
#pragma unroll
      for (int kk = 0; kk < 2; ++kk)
        bq0[n][kk] = ds_readv(aB[n][kk] + cb + 32768u);
  };
  auto RD_B1 = [&](uint32_t cb) {
#pragma unroll
    for (int n = 0; n < 2; ++n)
#pragma unroll
      for (int kk = 0; kk < 2; ++kk)
        bq1[n][kk] = ds_readv(aB[n][kk] + cb + 49152u);
  };

#define PRIO_ON  __builtin_amdgcn_s_setprio(1)
#define PRIO_OFF __builtin_amdgcn_s_setprio(0)

  // ---- prologue (same as r8): tile0 full + tile1 {A0,B0,B1}.
  STAGE(pA[0], 0, 0);   // A0(0)
  STAGE(pB[0], 0, 2);   // B0(0)
  STAGE(pB[1], 0, 3);   // B1(0)
  STAGE(pA[1], 0, 1);   // A1(0)
  STAGE(pA[0], 1, 0);   // A0(1)
  STAGE(pB[0], 1, 2);   // B0(1)
  STAGE(pB[1], 1, 3);   // B1(1)
  VM(6);                // tile 0 (oldest 8 gloads) landed
  BAR();

  const int niter = nk >> 1;
  for (int i = 0; i < niter - 1; ++i) {
    // ============ K-tile 2i (buf0, cb=0) ============
    RD_A0(0); RD_B0(0);                        // Ph1
    LGKM(8); VM(8);
    BAR(); LGKM(0);
    STAGE(pA[1], 1, 1);                        // A1(2i+1)
    PRIO_ON; Q1(); PRIO_OFF;
    RD_B1(0);                                  // Ph2
    VM(8);
    BAR(); LGKM(0);
    STAGE(pA[0], 0, 0);                        // A0(2i+2)
    PRIO_ON; Q2(); PRIO_OFF;
    RD_A1(0);                                  // Ph3
    BAR(); LGKM(0);
    STAGE(pB[0], 0, 2);                        // B0(2i+2)
    PRIO_ON; Q3(); PRIO_OFF;
    VM(8);                                     // Ph4
    BAR();
    STAGE(pB[1], 0, 3);                        // B1(2i+2)
    PRIO_ON; Q4(); PRIO_OFF;

    // ============ K-tile 2i+1 (buf1, cb=65536) ============
    RD_A0(65536u); RD_B0(65536u);              // Ph5
    LGKM(8); VM(8);
    BAR(); LGKM(0);
    STAGE(pA[1], 0, 1);                        // A1(2i+2)
    PRIO_ON; Q1(); PRIO_OFF;
    RD_B1(65536u);                             // Ph6
    VM(8);
    BAR(); LGKM(0);
    STAGE(pA[0], 1, 0);                        // A0(2i+3)
    PRIO_ON; Q2(); PRIO_OFF;
    RD_A1(65536u);                             // Ph7
    BAR(); LGKM(0);
    STAGE(pB[0], 1, 2);                        // B0(2i+3)
    PRIO_ON; Q3(); PRIO_OFF;
    VM(8);                                     // Ph8
    BAR();
    STAGE(pB[1], 1, 3);                        // B1(2i+3)
    PRIO_ON; Q4(); PRIO_OFF;
  }

  // ---- tail pair (t=nk-2 even / t=nk-1 odd): only stage = A1(nk-1);
  // VM(0) at the VM sites (full drain, safe with stages skipped).
  RD_A0(0); RD_B0(0);                          // Ph1
  LGKM(8); VM(0);
  BAR(); LGKM(0);
  STAGE(pA[1], 1, 1);                          // A1(nk-1)
  PRIO_ON; Q1(); PRIO_OFF;
  RD_B1(0);                                    // Ph2
  VM(0);
  BAR(); LGKM(0);
  PRIO_ON; Q2(); PRIO_OFF;
  RD_A1(0);                                    // Ph3
  BAR(); LGKM(0);
  PRIO_ON; Q3(); PRIO_OFF;
  BAR();                                       // Ph4
  PRIO_ON; Q4(); PRIO_OFF;

  RD_A0(65536u); RD_B0(65536u);                // Ph5
  LGKM(8);
  BAR(); LGKM(0);
  PRIO_ON; Q1(); PRIO_OFF;
  RD_B1(65536u);                               // Ph6
  BAR(); LGKM(0);
  PRIO_ON; Q2(); PRIO_OFF;
  RD_A1(65536u);                               // Ph7
  BAR(); LGKM(0);
  PRIO_ON; Q3(); PRIO_OFF;
  PRIO_ON; Q4(); PRIO_OFF;                     // Ph8

  // ---- epilogue (verified r5-r12): row = m*16+fr, cols = n*16+q*4+{0..3}
  const int q = lane >> 4;
  if (EPI == 0) {
    short* C = (short*)Cout;
#pragma unroll
    for (int m = 0; m < 8; ++m) {
      const int row = brow * 256 + wr * 128 + m * 16 + fr;
#pragma unroll
      for (int n = 0; n < 4; ++n) {
        const int col = bcol * 256 + wc * 64 + n * 16 + q * 4;
        const float4 bv = *(const float4*)&bias[col];
        short4 o;
        float v0 = acc[m][n][0] + bv.x; v0 = v0 > 0.f ? v0 * v0 : 0.f;
        float v1 = acc[m][n][1] + bv.y; v1 = v1 > 0.f ? v1 * v1 : 0.f;
        float v2 = acc[m][n][2] + bv.z; v2 = v2 > 0.f ? v2 * v2 : 0.f;
        float v3 = acc[m][n][3] + bv.w; v3 = v3 > 0.f ? v3 * v3 : 0.f;
        o.x = f2bf(v0); o.y = f2bf(v1); o.z = f2bf(v2); o.w = f2bf(v3);
        *(short4*)&C[(size_t)row * N + col] = o;
      }
    }
  } else {
    float* C = (float*)Cout;
#pragma unroll
    for (int m = 0; m < 8; ++m) {
      const int row = brow * 256 + wr * 128 + m * 16 + fr;
#pragma unroll
      for (int n = 0; n < 4; ++n) {
        const int col = bcol * 256 + wc * 64 + n * 16 + q * 4;
        const float4 bv = *(const float4*)&bias[col];
        float4 o;
        o.x = acc[m][n][0] + bv.x;
        o.y = acc[m][n][1] + bv.y;
        o.z = acc[m][n][2] + bv.z;
        o.w = acc[m][n][3] + bv.w;
        *(float4*)&C[(size_t)row * N + col] = o;
      }
    }
  }
#undef STAGE
}

// ---- launch -------------------------------------------------------------

extern "C" void kernel_launch(void* const* d_in, const int* in_sizes, int n_in,
                              void* d_out, int out_size, void* d_ws,
                              size_t ws_size, hipStream_t stream) {
  const float* x  = (const float*)d_in[0];
  const float* w1 = (const float*)d_in[1];
  const float* b1 = (const float*)d_in[2];
  const float* w2 = (const float*)d_in[3];
  const float* b2 = (const float*)d_in[4];
  float* out = (float*)d_out;

  const int H = in_sizes[2];            // 8192
  const int D = in_sizes[4];            // 2048
  const int M = in_sizes[0] / D;        // B*S = 8192

  short* xb  = (short*)d_ws;                 // M*D
  short* w1b = xb  + (size_t)M * D;          // H*D
  short* w2b = w1b + (size_t)H * D;          // D*H
  short* act = w2b + (size_t)D * H;          // M*H

  {
    int n4 = (M * D) / 4;
    cvt_f32_bf16<<<(n4 + 255) / 256, 256, 0, stream>>>(x, xb, n4);
    n4 = (H * D) / 4;
    cvt_f32_bf16<<<(n4 + 255) / 256, 256, 0, stream>>>(w1, w1b, n4);
    n4 = (D * H) / 4;
    cvt_f32_bf16<<<(n4 + 255) / 256, 256, 0, stream>>>(w2, w2b, n4);
  }

  // GEMM1: [M,D] @ [H,D]^T -> sqrelu -> act[M,H] (bf16)
  gemm_bt<0><<<(M / 256) * (H / 256), 512, 0, stream>>>(
      xb, w1b, b1, (void*)act, M, H, D);
  // GEMM2: [M,H] @ [D,H]^T -> + b2 -> out[M,D] (f32)
  gemm_bt<1><<<(M / 256) * (D / 256), 512, 0, stream>>>(
      act, w2b, b2, (void*)out, M, D, H);
}